// Round 1
// baseline (3569.773 us; speedup 1.0000x reference)
//
#include <hip/hip_runtime.h>
#include <math.h>

// Problem constants (reference: N=256, H=512, K=2048, B=256, ETA=1.0)
#define NSEQ 256
#define HDIM 512
#define KDS  2048
#define BB   256
#define NM   255   // N-1 prefix rows

// ---------------- workspace layout (floats) ----------------
// phiT    : HDIM*KDS            = 1,048,576   (phi_all transposed: [h][k])
// seqT    : NSEQ*BB             =    65,536   ([j][b])
// dsT     : NSEQ*KDS            =   524,288   ([n][k])
// hat     : NM*HDIM*BB          = 33,423,360  ([m][h][b])
// accum   : 2                                  (ce_sum, correct_count)
#define OFF_PHIT 0
#define OFF_SEQT (OFF_PHIT + HDIM*KDS)
#define OFF_DST  (OFF_SEQT + NSEQ*BB)
#define OFF_HAT  (OFF_DST + NSEQ*KDS)
#define OFF_ACC  (OFF_HAT + (size_t)NM*HDIM*BB)

__global__ void kzero(float* a) {
    if (threadIdx.x < 2) a[threadIdx.x] = 0.0f;
}

// transpose dataset (K,N)->(N,K) and sequences (B,N)->(N,B)
__global__ __launch_bounds__(256) void kernT(const float* __restrict__ ds,
                                             const float* __restrict__ seq,
                                             float* __restrict__ dsT,
                                             float* __restrict__ seqT) {
    int id = blockIdx.x * 256 + threadIdx.x;
    if (id < KDS * NSEQ) {
        int k = id >> 8, n = id & 255;
        dsT[n * KDS + k] = ds[id];
    }
    if (id < BB * NSEQ) {
        int b = id >> 8, n = id & 255;
        seqT[n * BB + b] = seq[id];
    }
}

// per-h: softmax(B_logits[h,:]) then phiT[h][k] = sum_n w[n]*dsT[n][k]
__global__ __launch_bounds__(256) void kernB(const float* __restrict__ B_logits,
                                             const float* __restrict__ dsT,
                                             float* __restrict__ phiT) {
    int h = blockIdx.x, t = threadIdx.x;
    __shared__ float w[NSEQ];
    __shared__ float red[8];
    float x = B_logits[h * NSEQ + t];
    float mx = x;
    #pragma unroll
    for (int off = 32; off; off >>= 1) mx = fmaxf(mx, __shfl_xor(mx, off));
    if ((t & 63) == 0) red[t >> 6] = mx;
    __syncthreads();
    mx = fmaxf(fmaxf(red[0], red[1]), fmaxf(red[2], red[3]));
    float e = __expf(x - mx);
    float s = e;
    #pragma unroll
    for (int off = 32; off; off >>= 1) s += __shfl_xor(s, off);
    if ((t & 63) == 0) red[4 + (t >> 6)] = s;
    __syncthreads();
    s = red[4] + red[5] + red[6] + red[7];
    w[t] = e / s;
    __syncthreads();

    float acc[8];
    #pragma unroll
    for (int kk = 0; kk < 8; ++kk) acc[kk] = 0.0f;
    for (int n = 0; n < NSEQ; ++n) {
        float wn = w[n];
        const float* dr = dsT + n * KDS + t;
        #pragma unroll
        for (int kk = 0; kk < 8; ++kk) acc[kk] = fmaf(wn, dr[kk * 256], acc[kk]);
    }
    #pragma unroll
    for (int kk = 0; kk < 8; ++kk) phiT[h * KDS + kk * 256 + t] = acc[kk];
}

// masked softmax over A_logits[m+1,h,0..m] then hat[m][h][b] = sum_j w[j]*seqT[j][b]
__global__ __launch_bounds__(256) void kernC(const float* __restrict__ A_logits,
                                             const float* __restrict__ seqT,
                                             float* __restrict__ hat) {
    int m = blockIdx.x;                 // 0..254 (prefix n = m+1)
    int wave = threadIdx.x >> 6, lane = threadIdx.x & 63;
    int h = blockIdx.y * 4 + wave;      // 0..511
    __shared__ float w4[4][NSEQ];
    const float* row = A_logits + ((size_t)(m + 1) * HDIM + h) * NSEQ;

    float x[4];
    float mx = -INFINITY;
    #pragma unroll
    for (int q = 0; q < 4; ++q) {
        int j = lane + q * 64;
        x[q] = (j <= m) ? row[j] : -INFINITY;
        mx = fmaxf(mx, x[q]);
    }
    #pragma unroll
    for (int off = 32; off; off >>= 1) mx = fmaxf(mx, __shfl_xor(mx, off));
    float e[4], s = 0.0f;
    #pragma unroll
    for (int q = 0; q < 4; ++q) {
        e[q] = (x[q] > -INFINITY) ? __expf(x[q] - mx) : 0.0f;
        s += e[q];
    }
    #pragma unroll
    for (int off = 32; off; off >>= 1) s += __shfl_xor(s, off);
    float inv = 1.0f / s;
    #pragma unroll
    for (int q = 0; q < 4; ++q) w4[wave][lane + q * 64] = e[q] * inv;
    __syncthreads();

    float4 acc = {0.f, 0.f, 0.f, 0.f};
    const float4* sT = (const float4*)seqT;
    for (int j = 0; j <= m; ++j) {
        float wj = w4[wave][j];
        float4 sv = sT[j * 64 + lane];
        acc.x = fmaf(wj, sv.x, acc.x);
        acc.y = fmaf(wj, sv.y, acc.y);
        acc.z = fmaf(wj, sv.z, acc.z);
        acc.w = fmaf(wj, sv.w, acc.w);
    }
    float4* out = (float4*)(hat + ((size_t)m * HDIM + h) * BB);
    out[lane] = acc;
}

// fused logits + online log-softmax + CE + argmax over k, per (m, 16-b tile)
__global__ __launch_bounds__(256) void kernD(const float* __restrict__ hat,
                                             const float* __restrict__ phiT,
                                             const int* __restrict__ indices,
                                             float* __restrict__ accum) {
    int m = blockIdx.x;
    int b0 = blockIdx.y * 16;
    int t = threadIdx.x;
    __shared__ float tile[HDIM * 16];   // [h][bb] 32 KB
    __shared__ float tgt[16];
    __shared__ int idxs[16];
    __shared__ float wm[4][16], wsum[4][16];
    __shared__ int wk[4][16];

    const float* hp = hat + (size_t)m * HDIM * BB + b0;
    #pragma unroll
    for (int i = 0; i < 32; ++i) {
        int e = t + i * 256;
        int h = e >> 4, bb = e & 15;
        tile[e] = hp[h * BB + bb];
    }
    if (t < 16) { idxs[t] = indices[b0 + t]; tgt[t] = 0.0f; }
    __syncthreads();

    float rm[16], rs[16];
    int rk[16];
    #pragma unroll
    for (int bb = 0; bb < 16; ++bb) { rm[bb] = -INFINITY; rs[bb] = 0.0f; rk[bb] = 0; }

    const float4* tile4 = (const float4*)tile;
    for (int kk = 0; kk < 4; ++kk) {
        int k0 = kk * 512 + t;          // second k is k0+256; monotone increasing per thread
        float a0[16], a1[16];
        #pragma unroll
        for (int bb = 0; bb < 16; ++bb) { a0[bb] = 0.0f; a1[bb] = 0.0f; }
        const float* pp = phiT + k0;
        for (int h = 0; h < HDIM; ++h) {
            float p0 = pp[h * KDS];
            float p1 = pp[h * KDS + 256];
            float4 u0 = tile4[h * 4 + 0];
            float4 u1 = tile4[h * 4 + 1];
            float4 u2 = tile4[h * 4 + 2];
            float4 u3 = tile4[h * 4 + 3];
            float tv[16] = {u0.x, u0.y, u0.z, u0.w, u1.x, u1.y, u1.z, u1.w,
                            u2.x, u2.y, u2.z, u2.w, u3.x, u3.y, u3.z, u3.w};
            #pragma unroll
            for (int bb = 0; bb < 16; ++bb) {
                a0[bb] = fmaf(p0, tv[bb], a0[bb]);
                a1[bb] = fmaf(p1, tv[bb], a1[bb]);
            }
        }
        // online updates: k0 first (lower), then k0+256
        #pragma unroll
        for (int bb = 0; bb < 16; ++bb) {
            float v = a0[bb];
            if (v > rm[bb]) { rs[bb] = rs[bb] * __expf(rm[bb] - v) + 1.0f; rm[bb] = v; rk[bb] = k0; }
            else rs[bb] += __expf(v - rm[bb]);
            if (k0 == idxs[bb]) tgt[bb] = v;
        }
        int k1 = k0 + 256;
        #pragma unroll
        for (int bb = 0; bb < 16; ++bb) {
            float v = a1[bb];
            if (v > rm[bb]) { rs[bb] = rs[bb] * __expf(rm[bb] - v) + 1.0f; rm[bb] = v; rk[bb] = k1; }
            else rs[bb] += __expf(v - rm[bb]);
            if (k1 == idxs[bb]) tgt[bb] = v;
        }
    }

    // wave-level butterfly combine of (max, sumexp, argmax)
    #pragma unroll
    for (int off = 32; off; off >>= 1) {
        #pragma unroll
        for (int bb = 0; bb < 16; ++bb) {
            float om = __shfl_xor(rm[bb], off);
            float os = __shfl_xor(rs[bb], off);
            int ok = __shfl_xor(rk[bb], off);
            float M = fmaxf(rm[bb], om);
            float ns = rs[bb] * __expf(rm[bb] - M) + os * __expf(om - M);
            bool take = (om > rm[bb]) || (om == rm[bb] && ok < rk[bb]);
            rk[bb] = take ? ok : rk[bb];
            rm[bb] = M;
            rs[bb] = ns;
        }
    }
    int wv = t >> 6, ln = t & 63;
    if (ln == 0) {
        #pragma unroll
        for (int bb = 0; bb < 16; ++bb) { wm[wv][bb] = rm[bb]; wsum[wv][bb] = rs[bb]; wk[wv][bb] = rk[bb]; }
    }
    __syncthreads();
    if (t < 64) {
        float ce = 0.0f, corr = 0.0f;
        if (t < 16) {
            float M = -INFINITY, S = 0.0f;
            int KA = 0x7fffffff;
            #pragma unroll
            for (int w = 0; w < 4; ++w) {
                float om = wm[w][t], os = wsum[w][t];
                int ok = wk[w][t];
                float Mn = fmaxf(M, om);
                S = S * __expf(M - Mn) + os * __expf(om - Mn);
                bool take = (om > M) || (om == M && ok < KA);
                KA = take ? ok : KA;
                M = Mn;
            }
            float lse = M + logf(S);
            ce = lse - tgt[t];
            corr = (KA == idxs[t]) ? 1.0f : 0.0f;
        }
        #pragma unroll
        for (int off = 32; off; off >>= 1) { ce += __shfl_xor(ce, off); corr += __shfl_xor(corr, off); }
        if (t == 0) { atomicAdd(&accum[0], ce); atomicAdd(&accum[1], corr); }
    }
}

__global__ void kfin(const float* __restrict__ accum, float* __restrict__ out) {
    if (threadIdx.x == 0) {
        const float inv = 1.0f / (255.0f * 256.0f);
        out[0] = accum[0] * inv;
        out[1] = accum[1] * inv;
    }
}

extern "C" void kernel_launch(void* const* d_in, const int* in_sizes, int n_in,
                              void* d_out, int out_size, void* d_ws, size_t ws_size,
                              hipStream_t stream) {
    const float* A_logits = (const float*)d_in[0];   // (256,512,256)
    const float* B_logits = (const float*)d_in[1];   // (512,256)
    const float* sequences = (const float*)d_in[2];  // (256,256)
    const float* dataset = (const float*)d_in[3];    // (2048,256)
    const int* indices = (const int*)d_in[4];        // (256,)
    float* out = (float*)d_out;

    float* ws = (float*)d_ws;
    float* phiT = ws + OFF_PHIT;
    float* seqT = ws + OFF_SEQT;
    float* dsT = ws + OFF_DST;
    float* hat = ws + OFF_HAT;
    float* accum = ws + OFF_ACC;

    kzero<<<1, 64, 0, stream>>>(accum);
    kernT<<<(KDS * NSEQ) / 256, 256, 0, stream>>>(dataset, sequences, dsT, seqT);
    kernB<<<HDIM, 256, 0, stream>>>(B_logits, dsT, phiT);
    kernC<<<dim3(NM, HDIM / 4), 256, 0, stream>>>(A_logits, seqT, hat);
    kernD<<<dim3(NM, BB / 16), 256, 0, stream>>>(hat, phiT, indices, accum);
    kfin<<<1, 64, 0, stream>>>(accum, out);
}

// Round 3
// 925.908 us; speedup vs baseline: 3.8554x; 3.8554x over previous
//
#include <hip/hip_runtime.h>
#include <math.h>

// Problem constants (reference: N=256, H=512, K=2048, B=256, ETA=1.0)
#define NSEQ 256
#define HDIM 512
#define KDS  2048
#define BB   256
#define NM   255   // N-1 prefix rows

typedef __attribute__((ext_vector_type(8))) short bf16x8;
typedef __attribute__((ext_vector_type(4))) float f32x4;

// ---------------- workspace layout (float slots) ----------------
#define OFF_PHIT  0                            // 1,048,576  f32 phi_all^T [h][k]
#define OFF_SEQT  1048576                      //    65,536  f32 seq^T [j][b]
#define OFF_DST   1114112                      //   524,288  f32 dataset^T [n][k]
#define OFF_ACC   1638400                      //        16  accum
#define OFF_PMAX  1638416                      // 2,088,960  per (m,b,kb32) max
#define OFF_PSUM  3727376                      // 2,088,960  per (m,b,kb32) sumexp
#define OFF_PARG  5816336                      // 2,088,960  per (m,b,kb32) argmax (int)
#define OFF_PTGT  7905296                      //    65,280  target logit per (m,b)
#define OFF_PHIKB 7970576                      //   524,288 slots = bf16 [k][h]
#define OFF_HATB  8494864                      // 16,711,680 slots = bf16 [m][b][h]
// end: 25,206,544 floats = 100.8 MB (< 140 MB proven available in round 1)

__device__ __forceinline__ ushort f2bf(float f) {
    unsigned u = __float_as_uint(f);
    unsigned r = (u + 0x7fffu + ((u >> 16) & 1u)) >> 16;   // RNE; NaN impossible here
    return (ushort)r;
}

__global__ void kzero(float* a) {
    if (threadIdx.x < 16) a[threadIdx.x] = 0.0f;
}

// transpose dataset (K,N)->(N,K) and sequences (B,N)->(N,B)
__global__ __launch_bounds__(256) void kernT(const float* __restrict__ ds,
                                             const float* __restrict__ seq,
                                             float* __restrict__ dsT,
                                             float* __restrict__ seqT) {
    int id = blockIdx.x * 256 + threadIdx.x;
    if (id < KDS * NSEQ) {
        int k = id >> 8, n = id & 255;
        dsT[n * KDS + k] = ds[id];
    }
    if (id < BB * NSEQ) {
        int b = id >> 8, n = id & 255;
        seqT[n * BB + b] = seq[id];
    }
}

// per-h: softmax(B_logits[h,:]) then phiT[h][k] = sum_n w[n]*dsT[n][k]
__global__ __launch_bounds__(256) void kernB(const float* __restrict__ B_logits,
                                             const float* __restrict__ dsT,
                                             float* __restrict__ phiT) {
    int h = blockIdx.x, t = threadIdx.x;
    __shared__ float w[NSEQ];
    __shared__ float red[8];
    float x = B_logits[h * NSEQ + t];
    float mx = x;
    #pragma unroll
    for (int off = 32; off; off >>= 1) mx = fmaxf(mx, __shfl_xor(mx, off));
    if ((t & 63) == 0) red[t >> 6] = mx;
    __syncthreads();
    mx = fmaxf(fmaxf(red[0], red[1]), fmaxf(red[2], red[3]));
    float e = __expf(x - mx);
    float s = e;
    #pragma unroll
    for (int off = 32; off; off >>= 1) s += __shfl_xor(s, off);
    if ((t & 63) == 0) red[4 + (t >> 6)] = s;
    __syncthreads();
    s = red[4] + red[5] + red[6] + red[7];
    w[t] = e / s;
    __syncthreads();

    float acc[8];
    #pragma unroll
    for (int kk = 0; kk < 8; ++kk) acc[kk] = 0.0f;
    for (int n = 0; n < NSEQ; ++n) {
        float wn = w[n];
        const float* dr = dsT + n * KDS + t;
        #pragma unroll
        for (int kk = 0; kk < 8; ++kk) acc[kk] = fmaf(wn, dr[kk * 256], acc[kk]);
    }
    #pragma unroll
    for (int kk = 0; kk < 8; ++kk) phiT[h * KDS + kk * 256 + t] = acc[kk];
}

// phiT f32 [h][k] -> phi_kb bf16 [k][h]
__global__ __launch_bounds__(256) void kernTB(const float* __restrict__ phiT,
                                              ushort* __restrict__ phikb) {
    __shared__ float tile[32][33];
    int h0 = blockIdx.x * 32, k0 = blockIdx.y * 32;
    int tc = threadIdx.x & 31, tr = threadIdx.x >> 5;   // 8 rows per pass
    #pragma unroll
    for (int i = 0; i < 4; ++i) {
        int r = tr + i * 8;
        tile[r][tc] = phiT[(size_t)(h0 + r) * KDS + k0 + tc];
    }
    __syncthreads();
    #pragma unroll
    for (int i = 0; i < 4; ++i) {
        int r = tr + i * 8;
        phikb[(size_t)(k0 + r) * HDIM + h0 + tc] = f2bf(tile[tc][r]);
    }
}

// masked softmax over A_logits[m+1,h,0..m]; hat[h][b] = sum_j w[j]*seqT[j][b];
// in-block transpose -> hatb bf16 [m][b][h]
__global__ __launch_bounds__(512) void kernC(const float* __restrict__ A_logits,
                                             const float* __restrict__ seqT,
                                             ushort* __restrict__ hatb) {
    int m = blockIdx.x;                 // 0..254 (prefix n = m+1)
    int wave = threadIdx.x >> 6, lane = threadIdx.x & 63;
    int h = blockIdx.y * 8 + wave;      // 0..511
    __shared__ float w8[8][NSEQ];
    __shared__ float trans[8][BB];
    const float* row = A_logits + ((size_t)(m + 1) * HDIM + h) * NSEQ;

    float x[4];
    float mx = -INFINITY;
    #pragma unroll
    for (int q = 0; q < 4; ++q) {
        int j = lane + q * 64;
        x[q] = (j <= m) ? row[j] : -INFINITY;
        mx = fmaxf(mx, x[q]);
    }
    #pragma unroll
    for (int off = 32; off; off >>= 1) mx = fmaxf(mx, __shfl_xor(mx, off));
    float e[4], s = 0.0f;
    #pragma unroll
    for (int q = 0; q < 4; ++q) {
        e[q] = (x[q] > -INFINITY) ? __expf(x[q] - mx) : 0.0f;
        s += e[q];
    }
    #pragma unroll
    for (int off = 32; off; off >>= 1) s += __shfl_xor(s, off);
    float inv = 1.0f / s;
    #pragma unroll
    for (int q = 0; q < 4; ++q) w8[wave][lane + q * 64] = e[q] * inv;
    __syncthreads();

    float4 acc = {0.f, 0.f, 0.f, 0.f};
    const float4* sT = (const float4*)seqT;
    for (int j = 0; j <= m; ++j) {
        float wj = w8[wave][j];
        float4 sv = sT[j * 64 + lane];
        acc.x = fmaf(wj, sv.x, acc.x);
        acc.y = fmaf(wj, sv.y, acc.y);
        acc.z = fmaf(wj, sv.z, acc.z);
        acc.w = fmaf(wj, sv.w, acc.w);
    }
    ((float4*)trans)[wave * 64 + lane] = acc;   // trans[wave][lane*4 + i]
    __syncthreads();

    if (threadIdx.x < 256) {
        int b = threadIdx.x;
        ushort u[8];
        #pragma unroll
        for (int i = 0; i < 8; ++i) u[i] = f2bf(trans[i][b]);
        int4 v;
        v.x = (int)u[0] | ((int)u[1] << 16);
        v.y = (int)u[2] | ((int)u[3] << 16);
        v.z = (int)u[4] | ((int)u[5] << 16);
        v.w = (int)u[6] | ((int)u[7] << 16);
        *(int4*)(hatb + ((size_t)m * BB + b) * HDIM + blockIdx.y * 8) = v;
    }
}

// MFMA GEMM: per (m, b-tile 128, k-tile 128): logits tile + online softmax partials.
// A = hatb[m] (b x h), B = phi_kb (k x h, read as KxN with contraction h).
#define LDST 144   // LDS row stride bytes (64 bf16 = 128B + 16B pad)
__global__ __launch_bounds__(256) void kernD(const ushort* __restrict__ hatb,
                                             const ushort* __restrict__ phikb,
                                             const int* __restrict__ indices,
                                             float* __restrict__ pmax,
                                             float* __restrict__ psum,
                                             int* __restrict__ parg,
                                             float* __restrict__ ptgt) {
    int m = blockIdx.x, bblk = blockIdx.y, kblk = blockIdx.z;
    int t = threadIdx.x, lane = t & 63, wave = t >> 6;
    int bhalf = wave & 1, khalf = wave >> 1;
    __shared__ int4 Al4[128 * LDST / 16];
    __shared__ int4 Bl4[128 * LDST / 16];
    char* Al = (char*)Al4;
    char* Bl = (char*)Bl4;
    __shared__ int idx_s[128];
    if (t < 128) idx_s[t] = indices[bblk * 128 + t];

    f32x4 acc[4][4];
    #pragma unroll
    for (int mb = 0; mb < 4; ++mb)
        #pragma unroll
        for (int nk = 0; nk < 4; ++nk)
            acc[mb][nk] = (f32x4){0.f, 0.f, 0.f, 0.f};

    const ushort* Abase = hatb + ((size_t)m * BB + bblk * 128) * HDIM;
    const ushort* Bbase = phikb + (size_t)kblk * 128 * HDIM;
    int l15 = lane & 15, lg = lane >> 4;

    for (int h0 = 0; h0 < HDIM; h0 += 64) {
        #pragma unroll
        for (int i = 0; i < 4; ++i) {
            int c = i * 256 + t;
            int row = c >> 3, c8 = c & 7;
            int4 va = *(const int4*)(Abase + (size_t)row * HDIM + h0 + c8 * 8);
            int4 vb = *(const int4*)(Bbase + (size_t)row * HDIM + h0 + c8 * 8);
            *(int4*)(Al + row * LDST + c8 * 16) = va;
            *(int4*)(Bl + row * LDST + c8 * 16) = vb;
        }
        __syncthreads();
        bf16x8 fa[4][2], fb[4][2];
        #pragma unroll
        for (int ks = 0; ks < 2; ++ks) {
            #pragma unroll
            for (int mb = 0; mb < 4; ++mb)
                fa[mb][ks] = *(const bf16x8*)(Al + (bhalf * 64 + mb * 16 + l15) * LDST + ks * 64 + lg * 16);
            #pragma unroll
            for (int nk = 0; nk < 4; ++nk)
                fb[nk][ks] = *(const bf16x8*)(Bl + (khalf * 64 + nk * 16 + l15) * LDST + ks * 64 + lg * 16);
        }
        #pragma unroll
        for (int ks = 0; ks < 2; ++ks)
            #pragma unroll
            for (int mb = 0; mb < 4; ++mb)
                #pragma unroll
                for (int nk = 0; nk < 4; ++nk)
                    acc[mb][nk] = __builtin_amdgcn_mfma_f32_16x16x32_bf16(fa[mb][ks], fb[nk][ks], acc[mb][nk], 0, 0, 0);
        __syncthreads();
    }

    // epilogue: per row, online (max, sumexp, argmax) over this block's 64-k wave range
    #pragma unroll
    for (int mb = 0; mb < 4; ++mb) {
        #pragma unroll
        for (int r = 0; r < 4; ++r) {
            int row_local = bhalf * 64 + mb * 16 + lg * 4 + r;
            int bg = bblk * 128 + row_local;
            int ib = idx_s[row_local];
            float M = -INFINITY, S = 0.0f;
            int KA = 0;
            #pragma unroll
            for (int nk = 0; nk < 4; ++nk) {
                float v = acc[mb][nk][r];
                int kg = kblk * 128 + khalf * 64 + nk * 16 + l15;
                if (v > M) { S = S * __expf(M - v) + 1.0f; M = v; KA = kg; }
                else S += __expf(v - M);
                if (kg == ib) ptgt[m * BB + bg] = v;
            }
            #pragma unroll
            for (int off = 1; off < 16; off <<= 1) {
                float om = __shfl_xor(M, off);
                float os = __shfl_xor(S, off);
                int ok = __shfl_xor(KA, off);
                float Mn = fmaxf(M, om);
                S = S * __expf(M - Mn) + os * __expf(om - Mn);
                bool take = (om > M) || (om == M && ok < KA);
                KA = take ? ok : KA;
                M = Mn;
            }
            if (l15 == 0) {
                size_t pidx = ((size_t)m * BB + bg) * 32 + kblk * 2 + khalf;
                pmax[pidx] = M;
                psum[pidx] = S;
                parg[pidx] = KA;
            }
        }
    }
}

// combine k-range partials -> CE + accuracy sums
__global__ __launch_bounds__(256) void kernE(const float* __restrict__ pmax,
                                             const float* __restrict__ psum,
                                             const int* __restrict__ parg,
                                             const float* __restrict__ ptgt,
                                             const int* __restrict__ indices,
                                             float* __restrict__ accum) {
    int m = blockIdx.x, b = threadIdx.x;
    size_t base = ((size_t)m * BB + b) * 32;
    float M = -INFINITY, S = 0.0f;
    int KA = 0;
    #pragma unroll 4
    for (int kb = 0; kb < 32; ++kb) {       // ascending k: strict > keeps first-index ties
        float om = pmax[base + kb], os = psum[base + kb];
        int ok = parg[base + kb];
        float Mn = fmaxf(M, om);
        S = S * __expf(M - Mn) + os * __expf(om - Mn);
        if (om > M) KA = ok;
        M = Mn;
    }
    float ce = M + logf(S) - ptgt[(size_t)m * BB + b];
    float corr = (KA == indices[b]) ? 1.0f : 0.0f;
    #pragma unroll
    for (int off = 32; off; off >>= 1) { ce += __shfl_xor(ce, off); corr += __shfl_xor(corr, off); }
    __shared__ float rc[4], rr[4];
    int wv = b >> 6;
    if ((b & 63) == 0) { rc[wv] = ce; rr[wv] = corr; }
    __syncthreads();
    if (b == 0) {
        atomicAdd(&accum[0], rc[0] + rc[1] + rc[2] + rc[3]);
        atomicAdd(&accum[1], rr[0] + rr[1] + rr[2] + rr[3]);
    }
}

__global__ void kfin(const float* __restrict__ accum, float* __restrict__ out) {
    if (threadIdx.x == 0) {
        const float inv = 1.0f / (255.0f * 256.0f);
        out[0] = accum[0] * inv;
        out[1] = accum[1] * inv;
    }
}

extern "C" void kernel_launch(void* const* d_in, const int* in_sizes, int n_in,
                              void* d_out, int out_size, void* d_ws, size_t ws_size,
                              hipStream_t stream) {
    const float* A_logits = (const float*)d_in[0];   // (256,512,256)
    const float* B_logits = (const float*)d_in[1];   // (512,256)
    const float* sequences = (const float*)d_in[2];  // (256,256)
    const float* dataset = (const float*)d_in[3];    // (2048,256)
    const int* indices = (const int*)d_in[4];        // (256,)
    float* out = (float*)d_out;

    float* ws = (float*)d_ws;
    float* phiT = ws + OFF_PHIT;
    float* seqT = ws + OFF_SEQT;
    float* dsT = ws + OFF_DST;
    float* accum = ws + OFF_ACC;
    float* pmax = ws + OFF_PMAX;
    float* psum = ws + OFF_PSUM;
    int* parg = (int*)(ws + OFF_PARG);
    float* ptgt = ws + OFF_PTGT;
    ushort* phikb = (ushort*)(ws + OFF_PHIKB);
    ushort* hatb = (ushort*)(ws + OFF_HATB);

    kzero<<<1, 64, 0, stream>>>(accum);
    kernT<<<(KDS * NSEQ) / 256, 256, 0, stream>>>(dataset, sequences, dsT, seqT);
    kernB<<<HDIM, 256, 0, stream>>>(B_logits, dsT, phiT);
    kernTB<<<dim3(HDIM / 32, KDS / 32), 256, 0, stream>>>(phiT, phikb);
    kernC<<<dim3(NM, HDIM / 8), 512, 0, stream>>>(A_logits, seqT, hatb);
    kernD<<<dim3(NM, 2, 16), 256, 0, stream>>>(hatb, phikb, indices, pmax, psum, parg, ptgt);
    kernE<<<NM, 256, 0, stream>>>(pmax, psum, parg, ptgt, indices, accum);
    kfin<<<1, 64, 0, stream>>>(accum, out);
}

// Round 4
// 471.333 us; speedup vs baseline: 7.5738x; 1.9644x over previous
//
#include <hip/hip_runtime.h>
#include <math.h>

// Problem constants (reference: N=256, H=512, K=2048, B=256, ETA=1.0)
#define NSEQ 256
#define HDIM 512
#define KDS  2048
#define BB   256
#define NM   255   // N-1 prefix rows

typedef __attribute__((ext_vector_type(8))) short bf16x8;
typedef __attribute__((ext_vector_type(4))) float f32x4;

// ---------------- workspace layout (float slots) ----------------
#define OFF_PHIT  0                            // 1,048,576  f32 phi_all^T [h][k]
#define OFF_DST   1048576                      //   524,288  f32 dataset^T [n][k]
#define OFF_ACC   1572864                      //        16  accum
#define OFF_PMAX  1572880                      // 2,088,960  per (m,b,kb32) max
#define OFF_PSUM  3661840                      // 2,088,960  per (m,b,kb32) sumexp
#define OFF_PARG  5750800                      // 2,088,960  per (m,b,kb32) argmax (int)
#define OFF_PTGT  7839760                      //    65,280  target logit per (m,b)
#define OFF_PHIKB 7905040                      //   524,288 slots = bf16 [k][h]
#define OFF_SEQB  8429328                      //    32,768 slots = bf16 [b][j]
#define OFF_HATB  8462096                      // 16,711,680 slots = bf16 [m][b][h]
// end: 25,173,776 floats = 100.7 MB (< 140 MB proven available in round 1)

__device__ __forceinline__ ushort f2bf(float f) {
    unsigned u = __float_as_uint(f);
    unsigned r = (u + 0x7fffu + ((u >> 16) & 1u)) >> 16;   // RNE; NaN impossible here
    return (ushort)r;
}

__global__ void kzero(float* a) {
    if (threadIdx.x < 16) a[threadIdx.x] = 0.0f;
}

// transpose dataset (K,N)->(N,K); convert sequences (B,N) f32 -> bf16 same layout
__global__ __launch_bounds__(256) void kernT(const float* __restrict__ ds,
                                             const float* __restrict__ seq,
                                             float* __restrict__ dsT,
                                             ushort* __restrict__ seqb) {
    int id = blockIdx.x * 256 + threadIdx.x;
    if (id < KDS * NSEQ) {
        int k = id >> 8, n = id & 255;
        dsT[n * KDS + k] = ds[id];
    }
    if (id < BB * NSEQ) seqb[id] = f2bf(seq[id]);
}

// per-h: softmax(B_logits[h,:]) then phiT[h][k] = sum_n w[n]*dsT[n][k]
__global__ __launch_bounds__(256) void kernB(const float* __restrict__ B_logits,
                                             const float* __restrict__ dsT,
                                             float* __restrict__ phiT) {
    int h = blockIdx.x, t = threadIdx.x;
    __shared__ float w[NSEQ];
    __shared__ float red[8];
    float x = B_logits[h * NSEQ + t];
    float mx = x;
    #pragma unroll
    for (int off = 32; off; off >>= 1) mx = fmaxf(mx, __shfl_xor(mx, off));
    if ((t & 63) == 0) red[t >> 6] = mx;
    __syncthreads();
    mx = fmaxf(fmaxf(red[0], red[1]), fmaxf(red[2], red[3]));
    float e = __expf(x - mx);
    float s = e;
    #pragma unroll
    for (int off = 32; off; off >>= 1) s += __shfl_xor(s, off);
    if ((t & 63) == 0) red[4 + (t >> 6)] = s;
    __syncthreads();
    s = red[4] + red[5] + red[6] + red[7];
    w[t] = e / s;
    __syncthreads();

    float acc[8];
    #pragma unroll
    for (int kk = 0; kk < 8; ++kk) acc[kk] = 0.0f;
    for (int n = 0; n < NSEQ; ++n) {
        float wn = w[n];
        const float* dr = dsT + n * KDS + t;
        #pragma unroll
        for (int kk = 0; kk < 8; ++kk) acc[kk] = fmaf(wn, dr[kk * 256], acc[kk]);
    }
    #pragma unroll
    for (int kk = 0; kk < 8; ++kk) phiT[h * KDS + kk * 256 + t] = acc[kk];
}

// phiT f32 [h][k] -> phi_kb bf16 [k][h]
__global__ __launch_bounds__(256) void kernTB(const float* __restrict__ phiT,
                                              ushort* __restrict__ phikb) {
    __shared__ float tile[32][33];
    int h0 = blockIdx.x * 32, k0 = blockIdx.y * 32;
    int tc = threadIdx.x & 31, tr = threadIdx.x >> 5;
    #pragma unroll
    for (int i = 0; i < 4; ++i) {
        int r = tr + i * 8;
        tile[r][tc] = phiT[(size_t)(h0 + r) * KDS + k0 + tc];
    }
    __syncthreads();
    #pragma unroll
    for (int i = 0; i < 4; ++i) {
        int r = tr + i * 8;
        phikb[(size_t)(k0 + r) * HDIM + h0 + tc] = f2bf(tile[tc][r]);
    }
}

// Fused: masked softmax of A_logits[m+1, ht*128..+128, :] -> bf16 weights in LDS,
// then MFMA  hat[b][h] = sum_j seq[b][j] * W[h][j]  -> hatb bf16 [m][b][h].
// LDS: 128 rows x 512B, XOR-swizzled (byte ^ ((row&7)<<4)) for conflict-free
// B-fragment ds_read_b128 (rows 0-7 -> disjoint 16B slots; 2-way aliasing = free).
__global__ __launch_bounds__(512) void kernC2(const float* __restrict__ A_logits,
                                              const ushort* __restrict__ seqb,
                                              ushort* __restrict__ hatb) {
    int m = blockIdx.x, ht = blockIdx.y;
    int t = threadIdx.x, lane = t & 63, wave = t >> 6;
    int bq = wave & 3, hhalf = wave >> 2;
    int l15 = lane & 15, lg = lane >> 4;
    __shared__ int4 Wl4[128 * 512 / 16];   // 64 KB
    char* Wl = (char*)Wl4;

    // phase 1: 8 waves x 16 rows each; one full-wave softmax per 256-wide row
    for (int rr = 0; rr < 16; ++rr) {
        int hl = wave + rr * 8;   // 0..127
        const float4* row = (const float4*)(A_logits + ((size_t)(m + 1) * HDIM + ht * 128 + hl) * NSEQ);
        float4 v = row[lane];
        int j0 = lane * 4;
        float x[4];
        x[0] = (j0 + 0 <= m) ? v.x : -INFINITY;
        x[1] = (j0 + 1 <= m) ? v.y : -INFINITY;
        x[2] = (j0 + 2 <= m) ? v.z : -INFINITY;
        x[3] = (j0 + 3 <= m) ? v.w : -INFINITY;
        float mx = fmaxf(fmaxf(x[0], x[1]), fmaxf(x[2], x[3]));
        #pragma unroll
        for (int off = 32; off; off >>= 1) mx = fmaxf(mx, __shfl_xor(mx, off));
        float e[4], s = 0.0f;
        #pragma unroll
        for (int q = 0; q < 4; ++q) {
            e[q] = (x[q] > -INFINITY) ? __expf(x[q] - mx) : 0.0f;
            s += e[q];
        }
        #pragma unroll
        for (int off = 32; off; off >>= 1) s += __shfl_xor(s, off);
        float inv = 1.0f / s;
        uint2 wv;
        wv.x = (unsigned)f2bf(e[0] * inv) | ((unsigned)f2bf(e[1] * inv) << 16);
        wv.y = (unsigned)f2bf(e[2] * inv) | ((unsigned)f2bf(e[3] * inv) << 16);
        int wo = (lane * 8) ^ ((hl & 7) << 4);
        *(uint2*)(Wl + hl * 512 + wo) = wv;
    }
    __syncthreads();

    // phase 2: per-wave 64b x 64h MFMA; A-fragments direct from global (L2-hot 128KB)
    f32x4 acc[4][4];
    #pragma unroll
    for (int mb = 0; mb < 4; ++mb)
        #pragma unroll
        for (int nk = 0; nk < 4; ++nk)
            acc[mb][nk] = (f32x4){0.f, 0.f, 0.f, 0.f};

    #pragma unroll
    for (int ks = 0; ks < 8; ++ks) {
        bf16x8 fa[4], fb[4];
        #pragma unroll
        for (int mb = 0; mb < 4; ++mb)
            fa[mb] = *(const bf16x8*)(seqb + (size_t)(bq * 64 + mb * 16 + l15) * NSEQ + ks * 32 + lg * 8);
        #pragma unroll
        for (int nk = 0; nk < 4; ++nk) {
            int hrow = hhalf * 64 + nk * 16 + l15;
            int co = (ks * 64 + lg * 16) ^ ((hrow & 7) << 4);
            fb[nk] = *(const bf16x8*)(Wl + hrow * 512 + co);
        }
        #pragma unroll
        for (int mb = 0; mb < 4; ++mb)
            #pragma unroll
            for (int nk = 0; nk < 4; ++nk)
                acc[mb][nk] = __builtin_amdgcn_mfma_f32_16x16x32_bf16(fa[mb], fb[nk], acc[mb][nk], 0, 0, 0);
    }

    // epilogue: C row = b (A-row), col = h (B-row); col=lane&15, row=(lane>>4)*4+reg
    #pragma unroll
    for (int mb = 0; mb < 4; ++mb)
        #pragma unroll
        for (int r = 0; r < 4; ++r) {
            int b = bq * 64 + mb * 16 + lg * 4 + r;
            #pragma unroll
            for (int nk = 0; nk < 4; ++nk) {
                int h = ht * 128 + hhalf * 64 + nk * 16 + l15;
                hatb[((size_t)m * BB + b) * HDIM + h] = f2bf(acc[mb][nk][r]);
            }
        }
}

// MFMA GEMM: per (m, b-tile 128, k-tile 128): logits tile + online softmax partials.
#define LDST 144   // LDS row stride bytes (64 bf16 = 128B + 16B pad)
__global__ __launch_bounds__(256) void kernD(const ushort* __restrict__ hatb,
                                             const ushort* __restrict__ phikb,
                                             const int* __restrict__ indices,
                                             float* __restrict__ pmax,
                                             float* __restrict__ psum,
                                             int* __restrict__ parg,
                                             float* __restrict__ ptgt) {
    int bblk = blockIdx.x, kblk = blockIdx.y, m = blockIdx.z;   // m slowest: 32 consecutive blocks share hatb[m]
    int t = threadIdx.x, lane = t & 63, wave = t >> 6;
    int bhalf = wave & 1, khalf = wave >> 1;
    __shared__ int4 Al4[128 * LDST / 16];
    __shared__ int4 Bl4[128 * LDST / 16];
    char* Al = (char*)Al4;
    char* Bl = (char*)Bl4;
    __shared__ int idx_s[128];
    if (t < 128) idx_s[t] = indices[bblk * 128 + t];

    f32x4 acc[4][4];
    #pragma unroll
    for (int mb = 0; mb < 4; ++mb)
        #pragma unroll
        for (int nk = 0; nk < 4; ++nk)
            acc[mb][nk] = (f32x4){0.f, 0.f, 0.f, 0.f};

    const ushort* Abase = hatb + ((size_t)m * BB + bblk * 128) * HDIM;
    const ushort* Bbase = phikb + (size_t)kblk * 128 * HDIM;
    int l15 = lane & 15, lg = lane >> 4;

    for (int h0 = 0; h0 < HDIM; h0 += 64) {
        #pragma unroll
        for (int i = 0; i < 4; ++i) {
            int c = i * 256 + t;
            int row = c >> 3, c8 = c & 7;
            int4 va = *(const int4*)(Abase + (size_t)row * HDIM + h0 + c8 * 8);
            int4 vb = *(const int4*)(Bbase + (size_t)row * HDIM + h0 + c8 * 8);
            *(int4*)(Al + row * LDST + c8 * 16) = va;
            *(int4*)(Bl + row * LDST + c8 * 16) = vb;
        }
        __syncthreads();
        bf16x8 fa[4][2], fb[4][2];
        #pragma unroll
        for (int ks = 0; ks < 2; ++ks) {
            #pragma unroll
            for (int mb = 0; mb < 4; ++mb)
                fa[mb][ks] = *(const bf16x8*)(Al + (bhalf * 64 + mb * 16 + l15) * LDST + ks * 64 + lg * 16);
            #pragma unroll
            for (int nk = 0; nk < 4; ++nk)
                fb[nk][ks] = *(const bf16x8*)(Bl + (khalf * 64 + nk * 16 + l15) * LDST + ks * 64 + lg * 16);
        }
        #pragma unroll
        for (int ks = 0; ks < 2; ++ks)
            #pragma unroll
            for (int mb = 0; mb < 4; ++mb)
                #pragma unroll
                for (int nk = 0; nk < 4; ++nk)
                    acc[mb][nk] = __builtin_amdgcn_mfma_f32_16x16x32_bf16(fa[mb][ks], fb[nk][ks], acc[mb][nk], 0, 0, 0);
        __syncthreads();
    }

    // epilogue: per row, online (max, sumexp, argmax) over this block's 64-k wave range
    #pragma unroll
    for (int mb = 0; mb < 4; ++mb) {
        #pragma unroll
        for (int r = 0; r < 4; ++r) {
            int row_local = bhalf * 64 + mb * 16 + lg * 4 + r;
            int bg = bblk * 128 + row_local;
            int ib = idx_s[row_local];
            float M = -INFINITY, S = 0.0f;
            int KA = 0;
            #pragma unroll
            for (int nk = 0; nk < 4; ++nk) {
                float v = acc[mb][nk][r];
                int kg = kblk * 128 + khalf * 64 + nk * 16 + l15;
                if (v > M) { S = S * __expf(M - v) + 1.0f; M = v; KA = kg; }
                else S += __expf(v - M);
                if (kg == ib) ptgt[m * BB + bg] = v;
            }
            #pragma unroll
            for (int off = 1; off < 16; off <<= 1) {
                float om = __shfl_xor(M, off);
                float os = __shfl_xor(S, off);
                int ok = __shfl_xor(KA, off);
                float Mn = fmaxf(M, om);
                S = S * __expf(M - Mn) + os * __expf(om - Mn);
                bool take = (om > M) || (om == M && ok < KA);
                KA = take ? ok : KA;
                M = Mn;
            }
            if (l15 == 0) {
                size_t pidx = ((size_t)m * BB + bg) * 32 + kblk * 2 + khalf;
                pmax[pidx] = M;
                psum[pidx] = S;
                parg[pidx] = KA;
            }
        }
    }
}

// combine k-range partials -> CE + accuracy sums
__global__ __launch_bounds__(256) void kernE(const float* __restrict__ pmax,
                                             const float* __restrict__ psum,
                                             const int* __restrict__ parg,
                                             const float* __restrict__ ptgt,
                                             const int* __restrict__ indices,
                                             float* __restrict__ accum) {
    int m = blockIdx.x, b = threadIdx.x;
    size_t base = ((size_t)m * BB + b) * 32;
    float M = -INFINITY, S = 0.0f;
    int KA = 0;
    #pragma unroll 4
    for (int kb = 0; kb < 32; ++kb) {       // ascending k: strict > keeps first-index ties
        float om = pmax[base + kb], os = psum[base + kb];
        int ok = parg[base + kb];
        float Mn = fmaxf(M, om);
        S = S * __expf(M - Mn) + os * __expf(om - Mn);
        if (om > M) KA = ok;
        M = Mn;
    }
    float ce = M + logf(S) - ptgt[(size_t)m * BB + b];
    float corr = (KA == indices[b]) ? 1.0f : 0.0f;
    #pragma unroll
    for (int off = 32; off; off >>= 1) { ce += __shfl_xor(ce, off); corr += __shfl_xor(corr, off); }
    __shared__ float rc[4], rr[4];
    int wv = b >> 6;
    if ((b & 63) == 0) { rc[wv] = ce; rr[wv] = corr; }
    __syncthreads();
    if (b == 0) {
        atomicAdd(&accum[0], rc[0] + rc[1] + rc[2] + rc[3]);
        atomicAdd(&accum[1], rr[0] + rr[1] + rr[2] + rr[3]);
    }
}

__global__ void kfin(const float* __restrict__ accum, float* __restrict__ out) {
    if (threadIdx.x == 0) {
        const float inv = 1.0f / (255.0f * 256.0f);
        out[0] = accum[0] * inv;
        out[1] = accum[1] * inv;
    }
}

extern "C" void kernel_launch(void* const* d_in, const int* in_sizes, int n_in,
                              void* d_out, int out_size, void* d_ws, size_t ws_size,
                              hipStream_t stream) {
    const float* A_logits = (const float*)d_in[0];   // (256,512,256)
    const float* B_logits = (const float*)d_in[1];   // (512,256)
    const float* sequences = (const float*)d_in[2];  // (256,256)
    const float* dataset = (const float*)d_in[3];    // (2048,256)
    const int* indices = (const int*)d_in[4];        // (256,)
    float* out = (float*)d_out;

    float* ws = (float*)d_ws;
    float* phiT = ws + OFF_PHIT;
    float* dsT = ws + OFF_DST;
    float* accum = ws + OFF_ACC;
    float* pmax = ws + OFF_PMAX;
    float* psum = ws + OFF_PSUM;
    int* parg = (int*)(ws + OFF_PARG);
    float* ptgt = ws + OFF_PTGT;
    ushort* phikb = (ushort*)(ws + OFF_PHIKB);
    ushort* seqb = (ushort*)(ws + OFF_SEQB);
    ushort* hatb = (ushort*)(ws + OFF_HATB);

    kzero<<<1, 64, 0, stream>>>(accum);
    kernT<<<(KDS * NSEQ) / 256, 256, 0, stream>>>(dataset, sequences, dsT, seqb);
    kernB<<<HDIM, 256, 0, stream>>>(B_logits, dsT, phiT);
    kernTB<<<dim3(HDIM / 32, KDS / 32), 256, 0, stream>>>(phiT, phikb);
    kernC2<<<dim3(NM, HDIM / 128), 512, 0, stream>>>(A_logits, seqb, hatb);
    kernD<<<dim3(2, 16, NM), 256, 0, stream>>>(hatb, phikb, indices, pmax, psum, parg, ptgt);
    kernE<<<NM, 256, 0, stream>>>(pmax, psum, parg, ptgt, indices, accum);
    kfin<<<1, 64, 0, stream>>>(accum, out);
}

// Round 5
// 400.138 us; speedup vs baseline: 8.9214x; 1.1779x over previous
//
#include <hip/hip_runtime.h>
#include <math.h>

// Problem constants (reference: N=256, H=512, K=2048, B=256, ETA=1.0)
#define NSEQ 256
#define HDIM 512
#define KDS  2048
#define BB   256
#define NM   255   // N-1 prefix rows

typedef __attribute__((ext_vector_type(8))) short bf16x8;
typedef __attribute__((ext_vector_type(4))) float f32x4;

#define AS1 __attribute__((address_space(1)))
#define AS3 __attribute__((address_space(3)))

// async global->LDS, 16B per lane; LDS dest = wave-uniform base + lane*16
__device__ __forceinline__ void gl16(const void* g, void* l) {
    __builtin_amdgcn_global_load_lds((AS1 const unsigned int*)g,
                                     (AS3 unsigned int*)l, 16, 0, 0);
}

// ---------------- workspace layout (float slots) ----------------
#define OFF_ACC   0            //        16
#define OFF_PMAX  16           // 2,088,960  per (m,b,32 k-groups) max
#define OFF_PSUM  2088976      // 2,088,960  sumexp
#define OFF_PARG  4177936      // 2,088,960  argmax (int)
#define OFF_PTGT  6266896      //    65,280  target logit per (m,b)
#define OFF_DSB   6332176      //   524,288 ushort = bf16 dataset [k][n]
#define OFF_SEQB  6594320      //    65,536 ushort = bf16 seq [b][j]
#define OFF_WBB   6627088      //   131,072 ushort = bf16 softmax(B_logits) [h][n]
#define OFF_PHIKB 6692624      // 1,048,576 ushort = bf16 phi [k][h]
#define OFF_HATB  7216912      // 33,423,360 ushort = bf16 hat [m][b][h]
// end: 23,928,592 floats = 95.7 MB (< 140 MB proven available)

__device__ __forceinline__ ushort f2bf(float f) {
    unsigned u = __float_as_uint(f);
    unsigned r = (u + 0x7fffu + ((u >> 16) & 1u)) >> 16;   // RNE; NaN impossible here
    return (ushort)r;
}

__global__ void kzero(float* a) {
    if (threadIdx.x < 16) a[threadIdx.x] = 0.0f;
}

// convert dataset (K,N) and sequences (B,N) f32 -> bf16, same layouts
__global__ __launch_bounds__(256) void kernT2(const float* __restrict__ ds,
                                              const float* __restrict__ seq,
                                              ushort* __restrict__ dsb,
                                              ushort* __restrict__ seqb) {
    int id = blockIdx.x * 256 + threadIdx.x;      // grid covers KDS*NSEQ exactly
    dsb[id] = f2bf(ds[id]);
    if (id < BB * NSEQ) seqb[id] = f2bf(seq[id]);
}

// softmax each row of B_logits (512 x 256) -> bf16 wBb [h][n]
__global__ __launch_bounds__(256) void kernSB(const float* __restrict__ B_logits,
                                              ushort* __restrict__ wBb) {
    int w = threadIdx.x >> 6, l = threadIdx.x & 63;
    int h = blockIdx.x * 4 + w;
    float4 v = ((const float4*)(B_logits + (size_t)h * NSEQ))[l];
    float mx = fmaxf(fmaxf(v.x, v.y), fmaxf(v.z, v.w));
    #pragma unroll
    for (int off = 32; off; off >>= 1) mx = fmaxf(mx, __shfl_xor(mx, off));
    float e[4] = {__expf(v.x - mx), __expf(v.y - mx), __expf(v.z - mx), __expf(v.w - mx)};
    float s = e[0] + e[1] + e[2] + e[3];
    #pragma unroll
    for (int off = 32; off; off >>= 1) s += __shfl_xor(s, off);
    float inv = 1.0f / s;
    uint2 o;
    o.x = (unsigned)f2bf(e[0] * inv) | ((unsigned)f2bf(e[1] * inv) << 16);
    o.y = (unsigned)f2bf(e[2] * inv) | ((unsigned)f2bf(e[3] * inv) << 16);
    *(uint2*)(wBb + (size_t)h * NSEQ + l * 4) = o;
}

// phi GEMM: phikb[k][h] = sum_n dsb[k][n] * wBb[h][n]; 128x128 tiles, 64 blocks.
#define LDST 144
__global__ __launch_bounds__(256) void kernP(const ushort* __restrict__ dsb,
                                             const ushort* __restrict__ wBb,
                                             ushort* __restrict__ phikb) {
    int kblk = blockIdx.x, hblk = blockIdx.y;
    int t = threadIdx.x, lane = t & 63, wave = t >> 6;
    int bhalf = wave & 1, khalf = wave >> 1;
    __shared__ int4 Al4[128 * LDST / 16];
    __shared__ int4 Bl4[128 * LDST / 16];
    char* Al = (char*)Al4;
    char* Bl = (char*)Bl4;
    f32x4 acc[4][4];
    #pragma unroll
    for (int mb = 0; mb < 4; ++mb)
        #pragma unroll
        for (int nk = 0; nk < 4; ++nk) acc[mb][nk] = (f32x4){0.f, 0.f, 0.f, 0.f};
    const ushort* Abase = dsb + (size_t)kblk * 128 * NSEQ;
    const ushort* Bbase = wBb + (size_t)hblk * 128 * NSEQ;
    int l15 = lane & 15, lg = lane >> 4;
    for (int n0 = 0; n0 < NSEQ; n0 += 64) {
        #pragma unroll
        for (int i = 0; i < 4; ++i) {
            int c = i * 256 + t;
            int row = c >> 3, c8 = c & 7;
            int4 va = *(const int4*)(Abase + (size_t)row * NSEQ + n0 + c8 * 8);
            int4 vb = *(const int4*)(Bbase + (size_t)row * NSEQ + n0 + c8 * 8);
            *(int4*)(Al + row * LDST + c8 * 16) = va;
            *(int4*)(Bl + row * LDST + c8 * 16) = vb;
        }
        __syncthreads();
        #pragma unroll
        for (int ks = 0; ks < 2; ++ks) {
            bf16x8 fa[4], fb[4];
            #pragma unroll
            for (int mb = 0; mb < 4; ++mb)
                fa[mb] = *(const bf16x8*)(Al + (bhalf * 64 + mb * 16 + l15) * LDST + ks * 64 + lg * 16);
            #pragma unroll
            for (int nk = 0; nk < 4; ++nk)
                fb[nk] = *(const bf16x8*)(Bl + (khalf * 64 + nk * 16 + l15) * LDST + ks * 64 + lg * 16);
            #pragma unroll
            for (int mb = 0; mb < 4; ++mb)
                #pragma unroll
                for (int nk = 0; nk < 4; ++nk)
                    acc[mb][nk] = __builtin_amdgcn_mfma_f32_16x16x32_bf16(fa[mb], fb[nk], acc[mb][nk], 0, 0, 0);
        }
        __syncthreads();
    }
    #pragma unroll
    for (int mb = 0; mb < 4; ++mb)
        #pragma unroll
        for (int r = 0; r < 4; ++r) {
            int krow = kblk * 128 + bhalf * 64 + mb * 16 + lg * 4 + r;
            #pragma unroll
            for (int nk = 0; nk < 4; ++nk) {
                int h = hblk * 128 + khalf * 64 + nk * 16 + l15;
                phikb[(size_t)krow * HDIM + h] = f2bf(acc[mb][nk][r]);
            }
        }
}

// Fused: masked softmax of A_logits[m+1, ht*128..+128, :] -> bf16 weights in LDS,
// then MFMA  hat[b][h] = sum_j seq[b][j] * W[h][j]  -> hatb bf16 [m][b][h].
__global__ __launch_bounds__(512) void kernC2(const float* __restrict__ A_logits,
                                              const ushort* __restrict__ seqb,
                                              ushort* __restrict__ hatb) {
    int m = blockIdx.x, ht = blockIdx.y;
    int t = threadIdx.x, lane = t & 63, wave = t >> 6;
    int bq = wave & 3, hhalf = wave >> 2;
    int l15 = lane & 15, lg = lane >> 4;
    __shared__ int4 Wl4[128 * 512 / 16];   // 64 KB
    char* Wl = (char*)Wl4;

    for (int rr = 0; rr < 16; ++rr) {
        int hl = wave + rr * 8;
        const float4* row = (const float4*)(A_logits + ((size_t)(m + 1) * HDIM + ht * 128 + hl) * NSEQ);
        float4 v = row[lane];
        int j0 = lane * 4;
        float x[4];
        x[0] = (j0 + 0 <= m) ? v.x : -INFINITY;
        x[1] = (j0 + 1 <= m) ? v.y : -INFINITY;
        x[2] = (j0 + 2 <= m) ? v.z : -INFINITY;
        x[3] = (j0 + 3 <= m) ? v.w : -INFINITY;
        float mx = fmaxf(fmaxf(x[0], x[1]), fmaxf(x[2], x[3]));
        #pragma unroll
        for (int off = 32; off; off >>= 1) mx = fmaxf(mx, __shfl_xor(mx, off));
        float e[4], s = 0.0f;
        #pragma unroll
        for (int q = 0; q < 4; ++q) {
            e[q] = (x[q] > -INFINITY) ? __expf(x[q] - mx) : 0.0f;
            s += e[q];
        }
        #pragma unroll
        for (int off = 32; off; off >>= 1) s += __shfl_xor(s, off);
        float inv = 1.0f / s;
        uint2 wv;
        wv.x = (unsigned)f2bf(e[0] * inv) | ((unsigned)f2bf(e[1] * inv) << 16);
        wv.y = (unsigned)f2bf(e[2] * inv) | ((unsigned)f2bf(e[3] * inv) << 16);
        int wo = (lane * 8) ^ ((hl & 7) << 4);
        *(uint2*)(Wl + hl * 512 + wo) = wv;
    }
    __syncthreads();

    f32x4 acc[4][4];
    #pragma unroll
    for (int mb = 0; mb < 4; ++mb)
        #pragma unroll
        for (int nk = 0; nk < 4; ++nk) acc[mb][nk] = (f32x4){0.f, 0.f, 0.f, 0.f};

    #pragma unroll
    for (int ks = 0; ks < 8; ++ks) {
        bf16x8 fa[4], fb[4];
        #pragma unroll
        for (int mb = 0; mb < 4; ++mb)
            fa[mb] = *(const bf16x8*)(seqb + (size_t)(bq * 64 + mb * 16 + l15) * NSEQ + ks * 32 + lg * 8);
        #pragma unroll
        for (int nk = 0; nk < 4; ++nk) {
            int hrow = hhalf * 64 + nk * 16 + l15;
            int co = (ks * 64 + lg * 16) ^ ((hrow & 7) << 4);
            fb[nk] = *(const bf16x8*)(Wl + hrow * 512 + co);
        }
        #pragma unroll
        for (int mb = 0; mb < 4; ++mb)
            #pragma unroll
            for (int nk = 0; nk < 4; ++nk)
                acc[mb][nk] = __builtin_amdgcn_mfma_f32_16x16x32_bf16(fa[mb], fb[nk], acc[mb][nk], 0, 0, 0);
    }

    #pragma unroll
    for (int mb = 0; mb < 4; ++mb)
        #pragma unroll
        for (int r = 0; r < 4; ++r) {
            int b = bq * 64 + mb * 16 + lg * 4 + r;
            #pragma unroll
            for (int nk = 0; nk < 4; ++nk) {
                int h = ht * 128 + hhalf * 64 + nk * 16 + l15;
                hatb[((size_t)m * BB + b) * HDIM + h] = f2bf(acc[mb][nk][r]);
            }
        }
}

// Logits GEMM, 256x256 tile: A = hatb[m] (256b x 512h), B = phikb k-tile (256k x 512h).
// 8 waves (2M x 4N, per-wave 128b x 64k), BK=64, double-buffered 128KB LDS,
// global_load_lds staging with pre-swizzled source; fused online-softmax epilogue.
__global__ __launch_bounds__(512, 2) void kernD(const ushort* __restrict__ hatb,
                                                const ushort* __restrict__ phikb,
                                                const int* __restrict__ indices,
                                                float* __restrict__ pmax,
                                                float* __restrict__ psum,
                                                int* __restrict__ parg,
                                                float* __restrict__ ptgt) {
    // XCD-chunked decode: all 8 kblks of one m land on one XCD, consecutively
    int id = blockIdx.x;                    // 0..2039
    int c = id & 7, pos = id >> 3;
    int lin = c * 255 + pos;
    int m = lin >> 3, kblk = lin & 7;

    int t = threadIdx.x, l = t & 63, w = t >> 6;
    int wm = w >> 2, wn = w & 3;
    int l15 = l & 15, lg = l >> 4;
    __shared__ char lds[2][65536];          // [buf][A 32KB | B 32KB]

    const char* Ab = (const char*)(hatb + (size_t)m * BB * HDIM);
    const char* Bb = (const char*)(phikb + (size_t)kblk * 256 * HDIM);
    // source pre-swizzle: LDS[row][c16] <- global[row][c16 ^ ((row&7)<<4)]
    int swz = (((l & 7) ^ (l >> 3)) << 4);

#define STAGE_D(dst, kt) { \
    char* la_ = (dst); \
    _Pragma("unroll") \
    for (int i_ = 0; i_ < 4; ++i_) { \
        int row_ = w * 32 + i_ * 8; \
        gl16(Ab + (size_t)(row_ + (l >> 3)) * 1024 + (kt) * 128 + swz, la_ + row_ * 128); \
        gl16(Bb + (size_t)(row_ + (l >> 3)) * 1024 + (kt) * 128 + swz, la_ + 32768 + row_ * 128); \
    } }

    STAGE_D(lds[0], 0);
    __syncthreads();

    f32x4 acc[8][4];
    #pragma unroll
    for (int mb = 0; mb < 8; ++mb)
        #pragma unroll
        for (int nk = 0; nk < 4; ++nk) acc[mb][nk] = (f32x4){0.f, 0.f, 0.f, 0.f};

    for (int kt = 0; kt < 8; ++kt) {
        int bf = kt & 1;
        if (kt < 7) STAGE_D(lds[bf ^ 1], kt + 1);
        char* A = lds[bf];
        char* B = lds[bf] + 32768;
        #pragma unroll
        for (int ks = 0; ks < 2; ++ks) {
            int col = (ks * 64 + lg * 16) ^ ((l15 & 7) << 4);
            bf16x8 fa[8], fb[4];
            #pragma unroll
            for (int mb = 0; mb < 8; ++mb)
                fa[mb] = *(const bf16x8*)(A + (wm * 128 + mb * 16 + l15) * 128 + col);
            #pragma unroll
            for (int nk = 0; nk < 4; ++nk)
                fb[nk] = *(const bf16x8*)(B + (wn * 64 + nk * 16 + l15) * 128 + col);
            #pragma unroll
            for (int mb = 0; mb < 8; ++mb)
                #pragma unroll
                for (int nk = 0; nk < 4; ++nk)
                    acc[mb][nk] = __builtin_amdgcn_mfma_f32_16x16x32_bf16(fa[mb], fb[nk], acc[mb][nk], 0, 0, 0);
        }
        __syncthreads();
    }
#undef STAGE_D

    // epilogue: per b-row, online (max, sumexp, argmax) over this wave's 64 k
    #pragma unroll
    for (int mb = 0; mb < 8; ++mb) {
        #pragma unroll
        for (int r = 0; r < 4; ++r) {
            int row_local = wm * 128 + mb * 16 + lg * 4 + r;   // b index 0..255
            int ib = indices[row_local];
            float M = -INFINITY, S = 0.0f;
            int KA = 0;
            #pragma unroll
            for (int nk = 0; nk < 4; ++nk) {
                float v = acc[mb][nk][r];
                int kg = kblk * 256 + wn * 64 + nk * 16 + l15;
                if (v > M) { S = S * __expf(M - v) + 1.0f; M = v; KA = kg; }
                else S += __expf(v - M);
                if (kg == ib) ptgt[m * BB + row_local] = v;
            }
            #pragma unroll
            for (int off = 1; off < 16; off <<= 1) {
                float om = __shfl_xor(M, off);
                float os = __shfl_xor(S, off);
                int ok = __shfl_xor(KA, off);
                float Mn = fmaxf(M, om);
                S = S * __expf(M - Mn) + os * __expf(om - Mn);
                bool take = (om > M) || (om == M && ok < KA);
                KA = take ? ok : KA;
                M = Mn;
            }
            if (l15 == 0) {
                size_t pidx = ((size_t)m * BB + row_local) * 32 + kblk * 4 + wn;
                pmax[pidx] = M;
                psum[pidx] = S;
                parg[pidx] = KA;
            }
        }
    }
}

// combine 32 k-range partials per (m,b) -> CE + accuracy sums
__global__ __launch_bounds__(256) void kernE(const float* __restrict__ pmax,
                                             const float* __restrict__ psum,
                                             const int* __restrict__ parg,
                                             const float* __restrict__ ptgt,
                                             const int* __restrict__ indices,
                                             float* __restrict__ accum) {
    int m = blockIdx.x, b = threadIdx.x;
    size_t base = ((size_t)m * BB + b) * 32;
    float M = -INFINITY, S = 0.0f;
    int KA = 0;
    #pragma unroll 4
    for (int kb = 0; kb < 32; ++kb) {       // ascending k: strict > keeps first-index ties
        float om = pmax[base + kb], os = psum[base + kb];
        int ok = parg[base + kb];
        float Mn = fmaxf(M, om);
        S = S * __expf(M - Mn) + os * __expf(om - Mn);
        if (om > M) KA = ok;
        M = Mn;
    }
    float ce = M + logf(S) - ptgt[(size_t)m * BB + b];
    float corr = (KA == indices[b]) ? 1.0f : 0.0f;
    #pragma unroll
    for (int off = 32; off; off >>= 1) { ce += __shfl_xor(ce, off); corr += __shfl_xor(corr, off); }
    __shared__ float rc[4], rr[4];
    int wv = b >> 6;
    if ((b & 63) == 0) { rc[wv] = ce; rr[wv] = corr; }
    __syncthreads();
    if (b == 0) {
        atomicAdd(&accum[0], rc[0] + rc[1] + rc[2] + rc[3]);
        atomicAdd(&accum[1], rr[0] + rr[1] + rr[2] + rr[3]);
    }
}

__global__ void kfin(const float* __restrict__ accum, float* __restrict__ out) {
    if (threadIdx.x == 0) {
        const float inv = 1.0f / (255.0f * 256.0f);
        out[0] = accum[0] * inv;
        out[1] = accum[1] * inv;
    }
}

extern "C" void kernel_launch(void* const* d_in, const int* in_sizes, int n_in,
                              void* d_out, int out_size, void* d_ws, size_t ws_size,
                              hipStream_t stream) {
    const float* A_logits = (const float*)d_in[0];   // (256,512,256)
    const float* B_logits = (const float*)d_in[1];   // (512,256)
    const float* sequences = (const float*)d_in[2];  // (256,256)
    const float* dataset = (const float*)d_in[3];    // (2048,256)
    const int* indices = (const int*)d_in[4];        // (256,)
    float* out = (float*)d_out;

    float* ws = (float*)d_ws;
    float* accum = ws + OFF_ACC;
    float* pmax = ws + OFF_PMAX;
    float* psum = ws + OFF_PSUM;
    int* parg = (int*)(ws + OFF_PARG);
    float* ptgt = ws + OFF_PTGT;
    ushort* dsb = (ushort*)(ws + OFF_DSB);
    ushort* seqb = (ushort*)(ws + OFF_SEQB);
    ushort* wBb = (ushort*)(ws + OFF_WBB);
    ushort* phikb = (ushort*)(ws + OFF_PHIKB);
    ushort* hatb = (ushort*)(ws + OFF_HATB);

    kzero<<<1, 64, 0, stream>>>(accum);
    kernT2<<<(KDS * NSEQ) / 256, 256, 0, stream>>>(dataset, sequences, dsb, seqb);
    kernSB<<<HDIM / 4, 256, 0, stream>>>(B_logits, wBb);
    kernP<<<dim3(KDS / 128, HDIM / 128), 256, 0, stream>>>(dsb, wBb, phikb);
    kernC2<<<dim3(NM, HDIM / 128), 512, 0, stream>>>(A_logits, seqb, hatb);
    kernD<<<NM * 8, 512, 0, stream>>>(hatb, phikb, indices, pmax, psum, parg, ptgt);
    kernE<<<NM, 256, 0, stream>>>(pmax, psum, parg, ptgt, indices, accum);
    kfin<<<1, 64, 0, stream>>>(accum, out);
}